// Round 3
// baseline (71.274 us; speedup 1.0000x reference)
//
#include <hip/hip_runtime.h>

#define B  32
#define HW 3136
#define C  256
#define HWC (HW*C)                  // 802816
#define CR 16                       // C / ratio
#define NCHUNK 16
#define POS_PER_CHUNK (HW/NCHUNK)   // 196
#define ITERS (POS_PER_CHUNK/4)     // 49

typedef float vf4 __attribute__((ext_vector_type(4)));

// ---- Kernel 1: partial spatial sums + (last block per batch) excite MLP ----
// partial[b][chunk][c] lives in d_out (scratch; fully overwritten by scale).
// ws: [0 .. 4KB) per-batch counters (128-B stride); [4KB .. 36KB) exc[B][C].
__global__ __launch_bounds__(256) void se_reduce_excite(
        const float* __restrict__ in, float* __restrict__ partial,
        const float* __restrict__ W1, const float* __restrict__ b1,
        const float* __restrict__ W2, const float* __restrict__ b2,
        unsigned* __restrict__ ctr, float* __restrict__ exc) {
    const int b     = blockIdx.x >> 4;     // NCHUNK == 16
    const int chunk = blockIdx.x & 15;
    const int t  = threadIdx.x;
    const int c4 = t & 63;                 // channel quad index (C/4 == 64)
    const int g  = t >> 6;                 // position group 0..3

    const vf4* p = (const vf4*)(in + (size_t)b * HWC
                                   + (size_t)(chunk * POS_PER_CHUNK + g) * C)
                   + c4;
    vf4 acc = {0.f, 0.f, 0.f, 0.f};
    #pragma unroll 7
    for (int i = 0; i < ITERS; ++i)
        acc += p[(size_t)i * 4 * (C/4)];

    __shared__ vf4 red[256];
    red[t] = acc;
    __syncthreads();
    if (t < 64) {
        vf4 s = red[t] + red[t+64] + red[t+128] + red[t+192];
        ((vf4*)(partial + ((size_t)b * NCHUNK + chunk) * C))[t] = s;
    }
    __syncthreads();

    // ---- last-block-per-batch detection (replay-safe: residue mod 16) ----
    __shared__ int sh_last;
    if (t == 0) {
        __threadfence();                           // release: partials visible
        unsigned old = atomicAdd(&ctr[b * 32], 1u);
        sh_last = ((old & 15u) == 15u);
    }
    __syncthreads();
    if (!sh_last) return;

    __threadfence();                               // acquire: see all partials
    __shared__ float sq[C];
    __shared__ float h[CR];

    // finish the mean for batch b: thread t sums channel t across 16 chunks
    {
        float s = 0.f;
        const float* pp = partial + (size_t)b * NCHUNK * C + t;
        #pragma unroll
        for (int k = 0; k < NCHUNK; ++k) s += pp[k * C];
        sq[t] = s * (1.0f / HW);
    }
    __syncthreads();

    // dense1 + relu, parallel: group j = t>>4 (output), lane = t&15
    {
        const int j = t >> 4, lane = t & 15;
        float a = 0.f;
        #pragma unroll
        for (int k = 0; k < C / 16; ++k) {
            const int c = k * 16 + lane;
            a += sq[c] * W1[c * CR + j];
        }
        a += __shfl_xor(a, 1, 16);
        a += __shfl_xor(a, 2, 16);
        a += __shfl_xor(a, 4, 16);
        a += __shfl_xor(a, 8, 16);
        if (lane == 0) h[j] = fmaxf(a + b1[j], 0.0f);
    }
    __syncthreads();

    // dense2 + sigmoid: thread t = output channel
    {
        float a = b2[t];
        #pragma unroll
        for (int j = 0; j < CR; ++j) a += h[j] * W2[j * C + t];
        exc[b * C + t] = 1.0f / (1.0f + expf(-a));
    }
}

// ---- Kernel 2: out = in * exc[b][c] (proven round-1 form, plain stores) ----
__global__ __launch_bounds__(256) void se_scale(const float* __restrict__ in,
                                                const float* __restrict__ exc,
                                                float* __restrict__ out, int n4) {
    const int stride = gridDim.x * blockDim.x;
    const vf4* in4  = (const vf4*)in;
    const vf4* exc4 = (const vf4*)exc;
    vf4* out4 = (vf4*)out;
    for (int i = blockIdx.x * blockDim.x + threadIdx.x; i < n4; i += stride) {
        vf4 v = in4[i];
        const int b  = i / (HWC/4);      // 200704
        const int c4 = i & 63;           // channel quad (C innermost)
        v *= exc4[(b << 6) + c4];
        out4[i] = v;
    }
}

// ---- Fallback 3-kernel excite (only if ws_size < 36 KB; proven round-1) ----
__global__ __launch_bounds__(256) void se_excite(const float* __restrict__ partial,
                                                 const float* __restrict__ W1,
                                                 const float* __restrict__ b1,
                                                 const float* __restrict__ W2,
                                                 const float* __restrict__ b2,
                                                 float* __restrict__ exc) {
    const int b = blockIdx.x;
    const int t = threadIdx.x;
    __shared__ float sq[C];
    __shared__ float h[CR];

    float s = 0.f;
    const float* pp = partial + (size_t)b * NCHUNK * C + t;
    #pragma unroll
    for (int k = 0; k < NCHUNK; ++k) s += pp[k * C];
    sq[t] = s * (1.0f / HW);
    __syncthreads();

    if (t < CR) {
        float a = b1[t];
        #pragma unroll 8
        for (int c = 0; c < C; ++c) a += sq[c] * W1[c * CR + t];
        h[t] = fmaxf(a, 0.0f);
    }
    __syncthreads();

    float a = b2[t];
    #pragma unroll
    for (int j = 0; j < CR; ++j) a += h[j] * W2[j * C + t];
    exc[b * C + t] = 1.0f / (1.0f + expf(-a));
}

__global__ __launch_bounds__(256) void se_reduce(const float* __restrict__ in,
                                                 float* __restrict__ partial) {
    const int b     = blockIdx.x >> 4;
    const int chunk = blockIdx.x & 15;
    const int t  = threadIdx.x;
    const int c4 = t & 63;
    const int g  = t >> 6;

    const vf4* p = (const vf4*)(in + (size_t)b * HWC
                                   + (size_t)(chunk * POS_PER_CHUNK + g) * C)
                   + c4;
    vf4 acc = {0.f, 0.f, 0.f, 0.f};
    #pragma unroll 7
    for (int i = 0; i < ITERS; ++i)
        acc += p[(size_t)i * 4 * (C/4)];

    __shared__ vf4 red[256];
    red[t] = acc;
    __syncthreads();
    if (t < 64) {
        vf4 s = red[t] + red[t+64] + red[t+128] + red[t+192];
        ((vf4*)(partial + ((size_t)b * NCHUNK + chunk) * C))[t] = s;
    }
}

extern "C" void kernel_launch(void* const* d_in, const int* in_sizes, int n_in,
                              void* d_out, int out_size, void* d_ws, size_t ws_size,
                              hipStream_t stream) {
    const float* in = (const float*)d_in[0];
    const float* W1 = (const float*)d_in[1];
    const float* b1 = (const float*)d_in[2];
    const float* W2 = (const float*)d_in[3];
    const float* b2 = (const float*)d_in[4];
    float* out = (float*)d_out;

    float* partial = out;                          // 512 KB scratch in d_out

    if (ws_size >= (size_t)(4096 + B * C * sizeof(float))) {
        unsigned* ctr = (unsigned*)d_ws;           // 32 counters, 128-B stride
        float* exc = (float*)d_ws + 1024;          // at +4 KB, 32 KB
        se_reduce_excite<<<B * NCHUNK, 256, 0, stream>>>(in, partial, W1, b1,
                                                         W2, b2, ctr, exc);
        se_scale<<<2048, 256, 0, stream>>>(in, exc, out, (B * HWC) / 4);
    } else {
        float* exc = (float*)d_ws;                 // 32 KB
        se_reduce<<<B * NCHUNK, 256, 0, stream>>>(in, partial);
        se_excite<<<B, 256, 0, stream>>>(partial, W1, b1, W2, b2, exc);
        se_scale<<<2048, 256, 0, stream>>>(in, exc, out, (B * HWC) / 4);
    }
}

// Round 4
// 55.684 us; speedup vs baseline: 1.2800x; 1.2800x over previous
//
#include <hip/hip_runtime.h>

#define B  32
#define HW 3136
#define C  256
#define HWC (HW*C)                  // 802816
#define CR 16                       // C / ratio
#define NCHUNK 16
#define POS_PER_CHUNK (HW/NCHUNK)   // 196
#define ITERS (POS_PER_CHUNK/4)     // 49

typedef float vf4 __attribute__((ext_vector_type(4)));

// ---------------- Stage 1: partial spatial sums -> partial[b][chunk][c] ----
// (proven round-1 kernel, unchanged; partials staged in d_out scratch)
__global__ __launch_bounds__(256) void se_reduce(const float* __restrict__ in,
                                                 float* __restrict__ partial) {
    const int b     = blockIdx.x >> 4;     // NCHUNK == 16
    const int chunk = blockIdx.x & 15;
    const int t  = threadIdx.x;
    const int c4 = t & 63;                 // channel quad index (C/4 == 64)
    const int g  = t >> 6;                 // position group 0..3

    const vf4* p = (const vf4*)(in + (size_t)b * HWC
                                   + (size_t)(chunk * POS_PER_CHUNK + g) * C)
                   + c4;
    vf4 acc = {0.f, 0.f, 0.f, 0.f};
    #pragma unroll 7
    for (int i = 0; i < ITERS; ++i)
        acc += p[(size_t)i * 4 * (C/4)];

    __shared__ vf4 red[256];
    red[t] = acc;
    __syncthreads();
    if (t < 64) {
        vf4 s = red[t] + red[t+64] + red[t+128] + red[t+192];
        ((vf4*)(partial + ((size_t)b * NCHUNK + chunk) * C))[t] = s;
    }
}

// ---------------- Stage 2: finish mean + MLP, dense1 parallelized ----------
__global__ __launch_bounds__(256) void se_excite(const float* __restrict__ partial,
                                                 const float* __restrict__ W1,
                                                 const float* __restrict__ b1,
                                                 const float* __restrict__ W2,
                                                 const float* __restrict__ b2,
                                                 float* __restrict__ exc) {
    const int b = blockIdx.x;
    const int t = threadIdx.x;
    __shared__ float sq[C];
    __shared__ float h[CR];

    // finish mean: thread t sums channel t across 16 chunk-partials
    float s = 0.f;
    const float* pp = partial + (size_t)b * NCHUNK * C + t;
    #pragma unroll
    for (int k = 0; k < NCHUNK; ++k) s += pp[k * C];
    sq[t] = s * (1.0f / HW);
    __syncthreads();

    // dense1 + relu, parallel: output j = t>>4, lane = t&15 sums 16 channels
    {
        const int j = t >> 4, lane = t & 15;
        float a = 0.f;
        #pragma unroll
        for (int k = 0; k < C / 16; ++k) {
            const int c = k * 16 + lane;
            a += sq[c] * W1[c * CR + j];
        }
        a += __shfl_xor(a, 1, 16);
        a += __shfl_xor(a, 2, 16);
        a += __shfl_xor(a, 4, 16);
        a += __shfl_xor(a, 8, 16);
        if (lane == 0) h[j] = fmaxf(a + b1[j], 0.0f);
    }
    __syncthreads();

    // dense2 + sigmoid: thread t = output channel
    float a = b2[t];
    #pragma unroll
    for (int j = 0; j < CR; ++j) a += h[j] * W2[j * C + t];
    exc[b * C + t] = 1.0f / (1.0f + expf(-a));
}

// ---------------- Stage 3: out = in * exc[b][c], non-temporal stores -------
// NT stores keep the 103 MB input resident in L3/L2 instead of letting the
// (never-re-read) output stream evict it -> both streaming reads become
// cache hits across graph replays; HBM carries only the output write.
__global__ __launch_bounds__(256) void se_scale(const float* __restrict__ in,
                                                const float* __restrict__ exc,
                                                float* __restrict__ out, int n4) {
    const int stride = gridDim.x * blockDim.x;
    const vf4* in4  = (const vf4*)in;
    const vf4* exc4 = (const vf4*)exc;
    vf4* out4 = (vf4*)out;
    for (int i = blockIdx.x * blockDim.x + threadIdx.x; i < n4; i += stride) {
        vf4 v = in4[i];
        const int b  = i / (HWC/4);      // 200704
        const int c4 = i & 63;           // channel quad (C innermost)
        v *= exc4[(b << 6) + c4];
        __builtin_nontemporal_store(v, out4 + i);
    }
}

extern "C" void kernel_launch(void* const* d_in, const int* in_sizes, int n_in,
                              void* d_out, int out_size, void* d_ws, size_t ws_size,
                              hipStream_t stream) {
    const float* in = (const float*)d_in[0];
    const float* W1 = (const float*)d_in[1];
    const float* b1 = (const float*)d_in[2];
    const float* W2 = (const float*)d_in[3];
    const float* b2 = (const float*)d_in[4];
    float* out = (float*)d_out;

    float* partial = out;                  // 512 KB scratch; overwritten by scale
    float* exc = (float*)d_ws;             // 32 KB

    se_reduce<<<B * NCHUNK, 256, 0, stream>>>(in, partial);
    se_excite<<<B, 256, 0, stream>>>(partial, W1, b1, W2, b2, exc);
    se_scale<<<2048, 256, 0, stream>>>(in, exc, out, (B * HWC) / 4);
}

// Round 5
// 55.542 us; speedup vs baseline: 1.2832x; 1.0026x over previous
//
#include <hip/hip_runtime.h>

#define B  32
#define HW 3136
#define C  256
#define HWC (HW*C)                  // 802816
#define CR 16                       // C / ratio
#define NCHUNK 16
#define POS_PER_CHUNK (HW/NCHUNK)   // 196
#define ITERS (POS_PER_CHUNK/4)     // 49

typedef float vf4 __attribute__((ext_vector_type(4)));

// ---------------- Stage 1: partial spatial sums -> partial[b][chunk][c] ----
__global__ __launch_bounds__(256) void se_reduce(const float* __restrict__ in,
                                                 float* __restrict__ partial) {
    const int b     = blockIdx.x >> 4;     // NCHUNK == 16
    const int chunk = blockIdx.x & 15;
    const int t  = threadIdx.x;
    const int c4 = t & 63;                 // channel quad index (C/4 == 64)
    const int g  = t >> 6;                 // position group 0..3

    const vf4* p = (const vf4*)(in + (size_t)b * HWC
                                   + (size_t)(chunk * POS_PER_CHUNK + g) * C)
                   + c4;
    vf4 acc = {0.f, 0.f, 0.f, 0.f};
    #pragma unroll 7
    for (int i = 0; i < ITERS; ++i)
        acc += p[(size_t)i * 4 * (C/4)];

    __shared__ vf4 red[256];
    red[t] = acc;
    __syncthreads();
    if (t < 64) {
        vf4 s = red[t] + red[t+64] + red[t+128] + red[t+192];
        ((vf4*)(partial + ((size_t)b * NCHUNK + chunk) * C))[t] = s;
    }
}

// ---- Stage 2 (fused): parallel-MLP prologue + 196-position scale stream ---
// 512 blocks (16 per batch). Prologue: finish mean from L2-resident partials,
// dense1 parallel (16 out x 16 lanes, shfl reduce), dense2 -> ex[] in LDS.
// ~1 us prologue amortized over a 200 KB/block stream (3%), unlike R2's
// 3136-block serial-dense1 version (35%).
__global__ __launch_bounds__(256) void se_scale_fused(
        const float* __restrict__ in, const float* __restrict__ partial,
        const float* __restrict__ W1, const float* __restrict__ b1,
        const float* __restrict__ W2, const float* __restrict__ b2,
        float* __restrict__ out) {
    const int b     = blockIdx.x >> 4;
    const int chunk = blockIdx.x & 15;
    const int t = threadIdx.x;
    __shared__ float sq[C];
    __shared__ float h[CR];
    __shared__ float ex[C];

    // finish mean: thread t sums channel t across 16 chunk-partials (L2)
    {
        float s = 0.f;
        const float* pp = partial + (size_t)b * NCHUNK * C + t;
        #pragma unroll
        for (int k = 0; k < NCHUNK; ++k) s += pp[k * C];
        sq[t] = s * (1.0f / HW);
    }
    __syncthreads();

    // dense1 + relu, parallel: output j = t>>4, lane = t&15 sums 16 channels
    {
        const int j = t >> 4, lane = t & 15;
        float a = 0.f;
        #pragma unroll
        for (int k = 0; k < C / 16; ++k) {
            const int c = k * 16 + lane;
            a += sq[c] * W1[c * CR + j];
        }
        a += __shfl_xor(a, 1, 16);
        a += __shfl_xor(a, 2, 16);
        a += __shfl_xor(a, 4, 16);
        a += __shfl_xor(a, 8, 16);
        if (lane == 0) h[j] = fmaxf(a + b1[j], 0.0f);
    }
    __syncthreads();

    // dense2 + sigmoid: thread t = output channel
    {
        float a = b2[t];
        #pragma unroll
        for (int j = 0; j < CR; ++j) a += h[j] * W2[j * C + t];
        ex[t] = 1.0f / (1.0f + expf(-a));
    }
    __syncthreads();

    // stream: 196 positions, NT stores keep input L3-resident across replays
    const int c4 = t & 63;
    const int g  = t >> 6;
    const size_t base = (size_t)b * HWC + (size_t)(chunk * POS_PER_CHUNK + g) * C;
    const vf4* in4 = (const vf4*)(in + base) + c4;
    vf4*      out4 = (vf4*)(out + base) + c4;
    const vf4 e = ((const vf4*)ex)[c4];
    #pragma unroll 7
    for (int i = 0; i < ITERS; ++i) {
        vf4 v = in4[(size_t)i * 4 * (C/4)];
        v *= e;
        __builtin_nontemporal_store(v, out4 + (size_t)i * 4 * (C/4));
    }
}

// ---------------- Fallback: proven R4 3-kernel path (ws too small) ---------
__global__ __launch_bounds__(256) void se_excite(const float* __restrict__ partial,
                                                 const float* __restrict__ W1,
                                                 const float* __restrict__ b1,
                                                 const float* __restrict__ W2,
                                                 const float* __restrict__ b2,
                                                 float* __restrict__ exc) {
    const int b = blockIdx.x;
    const int t = threadIdx.x;
    __shared__ float sq[C];
    __shared__ float h[CR];

    float s = 0.f;
    const float* pp = partial + (size_t)b * NCHUNK * C + t;
    #pragma unroll
    for (int k = 0; k < NCHUNK; ++k) s += pp[k * C];
    sq[t] = s * (1.0f / HW);
    __syncthreads();

    {
        const int j = t >> 4, lane = t & 15;
        float a = 0.f;
        #pragma unroll
        for (int k = 0; k < C / 16; ++k) {
            const int c = k * 16 + lane;
            a += sq[c] * W1[c * CR + j];
        }
        a += __shfl_xor(a, 1, 16);
        a += __shfl_xor(a, 2, 16);
        a += __shfl_xor(a, 4, 16);
        a += __shfl_xor(a, 8, 16);
        if (lane == 0) h[j] = fmaxf(a + b1[j], 0.0f);
    }
    __syncthreads();

    float a = b2[t];
    #pragma unroll
    for (int j = 0; j < CR; ++j) a += h[j] * W2[j * C + t];
    exc[b * C + t] = 1.0f / (1.0f + expf(-a));
}

__global__ __launch_bounds__(256) void se_scale(const float* __restrict__ in,
                                                const float* __restrict__ exc,
                                                float* __restrict__ out, int n4) {
    const int stride = gridDim.x * blockDim.x;
    const vf4* in4  = (const vf4*)in;
    const vf4* exc4 = (const vf4*)exc;
    vf4* out4 = (vf4*)out;
    for (int i = blockIdx.x * blockDim.x + threadIdx.x; i < n4; i += stride) {
        vf4 v = in4[i];
        const int b  = i / (HWC/4);
        const int c4 = i & 63;
        v *= exc4[(b << 6) + c4];
        __builtin_nontemporal_store(v, out4 + i);
    }
}

extern "C" void kernel_launch(void* const* d_in, const int* in_sizes, int n_in,
                              void* d_out, int out_size, void* d_ws, size_t ws_size,
                              hipStream_t stream) {
    const float* in = (const float*)d_in[0];
    const float* W1 = (const float*)d_in[1];
    const float* b1 = (const float*)d_in[2];
    const float* W2 = (const float*)d_in[3];
    const float* b2 = (const float*)d_in[4];
    float* out = (float*)d_out;

    const size_t partial_bytes = (size_t)B * NCHUNK * C * sizeof(float);  // 512 KB

    if (ws_size >= partial_bytes) {          // confirmed true (R2 ran this branch)
        float* partial = (float*)d_ws;
        se_reduce<<<B * NCHUNK, 256, 0, stream>>>(in, partial);
        se_scale_fused<<<B * NCHUNK, 256, 0, stream>>>(in, partial, W1, b1, W2, b2, out);
    } else {
        float* partial = out;                // scratch in d_out, overwritten below
        float* exc = (float*)d_ws;           // 32 KB
        se_reduce<<<B * NCHUNK, 256, 0, stream>>>(in, partial);
        se_excite<<<B, 256, 0, stream>>>(partial, W1, b1, W2, b2, exc);
        se_scale<<<2048, 256, 0, stream>>>(in, exc, out, (B * HWC) / 4);
    }
}